// Round 8
// baseline (335.174 us; speedup 1.0000x reference)
//
#include <hip/hip_runtime.h>
#include <hip/hip_bf16.h>
#include <stdint.h>

// Problem dims (fixed by reference)
#define M_TOT 16384   // B*S rows of x
#define K_TOT 2048    // contraction dim (M_DIM)
#define N_TOT 2048    // output cols (N_DIM)

// 256x256 GEMM geometry, 2 phases per K-tile
#define BM 256
#define BN 256
#define BK 64
#define LDS_HALF (128 * 64)   // shorts per half-tile [128 rows][64 k]

#define W_BLOCKS 2048      // prep: blocks [0, 2048) build W rows
#define CAST_BLOCKS 16384  // prep: blocks [2048, 18432) cast x

typedef __attribute__((ext_vector_type(8))) short short8;
typedef __attribute__((ext_vector_type(4))) float float4v;
typedef __attribute__((ext_vector_type(8))) unsigned short ushort8;

__device__ __forceinline__ unsigned short f2bf_rne(float f) {
    union { float f; unsigned u; } a; a.f = f;
    unsigned r = a.u + 0x7FFFu + ((a.u >> 16) & 1u);  // round-to-nearest-even
    return (unsigned short)(r >> 16);
}

// ---- Prep: W densify (zero+scatter) AND x fp32->bf16 cast, ONE dispatch ----
__global__ __launch_bounds__(256) void prep_kernel(
    const float* __restrict__ x,
    const float* __restrict__ val, const int* __restrict__ idx,
    const int* __restrict__ indptr,
    unsigned short* __restrict__ xb, unsigned short* __restrict__ Wb) {
    const int b = blockIdx.x;
    if (b < W_BLOCKS) {
        const int n = b;
        unsigned short* row = Wb + (size_t)n * K_TOT;
        ushort8 z = {0, 0, 0, 0, 0, 0, 0, 0};
        ((ushort8*)row)[threadIdx.x] = z;
        __syncthreads();
        const int s = indptr[n], e = indptr[n + 1];
        for (int j = s + (int)threadIdx.x; j < e; j += (int)blockDim.x)
            row[idx[j]] = f2bf_rne(val[j]);
    } else {
        const int i = (b - W_BLOCKS) * 256 + (int)threadIdx.x;  // 8-float chunk id
        const float4* xf = (const float4*)x;
        float4 a = xf[2 * i];
        float4 c = xf[2 * i + 1];
        ushort8 o;
        o[0] = f2bf_rne(a.x); o[1] = f2bf_rne(a.y); o[2] = f2bf_rne(a.z); o[3] = f2bf_rne(a.w);
        o[4] = f2bf_rne(c.x); o[5] = f2bf_rne(c.y); o[6] = f2bf_rne(c.z); o[7] = f2bf_rne(c.w);
        ((ushort8*)xb)[i] = o;
    }
}

// ---- 256x256 GEMM, 2 phases per K-tile: C = A * W^T + bias ----
// Round-7 profile: per K-tile wall 4420 cyc vs 2480 MFMA floor — the ~1940
// slack is 4x per-phase boundary cost (barrier skew + head-lgkm latency +
// stage issue). Since BOTH B halves persist in registers, the two quadrants
// sharing an A-half merge into ONE 32-MFMA cluster with zero extra regs ->
// 2 phases per K-tile, halving boundary count.
//   alpha(T): [lgkm0][32 MFMA: A0 x B0,B1][tail: RD A1]          (no barrier!)
//   beta(T):  [lgkm0][BAR][32 MFMA: A1 x B0,B1][stage T+2 (8 loads)]
//             [vmcnt(8)][BAR][RD A0,B0,B1 <- other buf (16 reads)]
// Hazards: beta-head = drain(lgkm0) THEN barrier -> all waves' reads of BUF
// are complete before any wave stages into BUF (same strength as rounds 5-7).
// vmcnt ledger (retires in issue order): enter alpha with 8 outstanding
// (other buf); beta stages 8 -> 16; vmcnt(8) retires exactly the 8 of the
// buffer the tail reads. MFMA cluster ks-OUTER (16 independent + 16 partners
// 16 insts away). Swizzle: LDS slot s of row r holds global 16B chunk s^(r&7)
// (pre-swizzled global source; LDS dest lane-linear; measured 0 conflicts).
__global__ __launch_bounds__(512, 2) void gemm_bias_kernel_256(
    const unsigned short* __restrict__ A,   // [M_TOT][K_TOT] bf16
    const unsigned short* __restrict__ Bw,  // [N_TOT][K_TOT] bf16
    const float* __restrict__ bias,         // [N_TOT]
    float* __restrict__ C)                  // [M_TOT][N_TOT] fp32
{
    extern __shared__ unsigned short lds[];  // 131072 B dynamic

    const int tid  = threadIdx.x;
    const int lane = tid & 63;
    const int wave = tid >> 6;              // 0..7

    // XCD-aware bijective swizzle: 512 blocks, 64 per XCD, bn fastest inside
    const int raw = blockIdx.x;
    const int lid = (raw & 7) * 64 + (raw >> 3);
    const int bm = lid >> 3;                // 0..63
    const int bn = lid & 7;                 // 0..7

    const int wrow = wave >> 2;             // 0..1
    const int wcol = wave & 3;              // 0..3
    const int wr16 = wrow * 16;
    const int wc16 = wcol * 16;
    const int mrow = lane & 15;
    const int quad = lane >> 4;
    const int rx   = mrow & 7;              // row&7 for swizzle (bases %8==0)

    // staging: per global_load_lds, wave covers 8 rows x 8 chunks of 16B;
    // source chunk = (lane&7)^(row&7) pre-swizzled, LDS dest lane-linear.
    const int srow = lane >> 3;                     // 0..7
    const int csrc = ((lane & 7) ^ srow) * 8;       // bf16 elem offset in row
    const unsigned short* pA = A  + (size_t)(bm * BM + wave * 8 + srow) * K_TOT + csrc;
    const unsigned short* pB = Bw + (size_t)(bn * BN + wave * 8 + srow) * K_TOT + csrc;
    unsigned short* lw = lds + wave * 8 * 64;       // per-wave LDS row base

    float4v acc[8][4] = {};
    short8 af[4][2];        // A fragments of the current A-half
    short8 bfr[2][2][2];    // B fragments, BOTH halves persistent [nh][ni][ks]

#define STAGE(PG, MATIDX, BUF, H, K0)                                            \
    { _Pragma("unroll")                                                          \
      for (int l = 0; l < 2; ++l) {                                              \
        const unsigned short* g = (PG) + ((size_t)((H) * 128 + l * 64) * K_TOT + (size_t)(K0)); \
        unsigned short* lp = lw + (((BUF) * 4 + (MATIDX) * 2 + (H)) * LDS_HALF) + l * 64 * 64;  \
        __builtin_amdgcn_global_load_lds(                                        \
            (const __attribute__((address_space(1))) unsigned int*)g,            \
            (__attribute__((address_space(3))) unsigned int*)lp, 16, 0, 0);      \
      } }

// all 4 halves of one K-tile (8 loads): A0,A1,B0,B1 -> BUF
#define STAGE4(BUF, K0)                                                          \
    STAGE(pA, 0, BUF, 0, K0) STAGE(pA, 0, BUF, 1, K0)                            \
    STAGE(pB, 1, BUF, 0, K0) STAGE(pB, 1, BUF, 1, K0)

#define RD_A(RBUF, RMH)                                                          \
    { const unsigned short* Ah = lds + ((RBUF) * 4 + (RMH)) * LDS_HALF;          \
      _Pragma("unroll")                                                          \
      for (int mi = 0; mi < 4; ++mi) {                                           \
        const int r = mi * 32 + wr16 + mrow;                                     \
        _Pragma("unroll")                                                        \
        for (int ks = 0; ks < 2; ++ks)                                           \
          af[mi][ks] = *(const short8*)(Ah + r * 64 + (((ks * 4 + quad) ^ rx) * 8)); \
      } }

#define RD_B(RBUF, RNH)                                                          \
    { const unsigned short* Bh = lds + ((RBUF) * 4 + 2 + (RNH)) * LDS_HALF;      \
      _Pragma("unroll")                                                          \
      for (int ni = 0; ni < 2; ++ni) {                                           \
        const int r = ni * 64 + wc16 + mrow;                                     \
        _Pragma("unroll")                                                        \
        for (int ks = 0; ks < 2; ++ks)                                           \
          bfr[RNH][ni][ks] = *(const short8*)(Bh + r * 64 + (((ks * 4 + quad) ^ rx) * 8)); \
      } }

// next tile's alpha operands: A0 + both B halves (16 ds_read_b128)
#define RD16(RBUF)  RD_A(RBUF, 0); RD_B(RBUF, 0); RD_B(RBUF, 1);

#define BARX { asm volatile("" ::: "memory"); __builtin_amdgcn_s_barrier(); asm volatile("" ::: "memory"); }
#define LGKM0 asm volatile("s_waitcnt lgkmcnt(0)" ::: "memory")
#define WAITV8 asm volatile("s_waitcnt vmcnt(8)" ::: "memory")
#define WAITV0 asm volatile("s_waitcnt vmcnt(0)" ::: "memory")
#define NOSTG ((void)0)

// 32 MFMAs (one A-half x both B-halves), ks-outer: 16 independent + 16
// partners each 16 instructions from their producer.
#define CLUSTER(MH)                                                              \
    _Pragma("unroll")                                                            \
    for (int ks = 0; ks < 2; ++ks)                                               \
      _Pragma("unroll")                                                          \
      for (int mi = 0; mi < 4; ++mi)                                             \
        _Pragma("unroll")                                                        \
        for (int nh = 0; nh < 2; ++nh)                                           \
          _Pragma("unroll")                                                      \
          for (int ni = 0; ni < 2; ++ni)                                         \
            acc[(MH) * 4 + mi][nh * 2 + ni] =                                    \
                __builtin_amdgcn_mfma_f32_16x16x32_bf16(                         \
                    af[mi][ks], bfr[nh][ni][ks], acc[(MH) * 4 + mi][nh * 2 + ni], 0, 0, 0);

// alpha: consume A0; tail-read A1 (same buf). No barrier.
#define ALPHA(BUF)                                                               \
  { LGKM0;                                                                       \
    __builtin_amdgcn_s_setprio(1);                                               \
    CLUSTER(0)                                                                   \
    __builtin_amdgcn_s_setprio(0);                                               \
    RD_A(BUF, 1); }

// beta: drain, barrier, consume A1; stage next-next tile into BUF; counted
// vmcnt; barrier; read next tile's alpha operands from the OTHER buf.
#define BETA(BUF, STGS, WT, RDS)                                                 \
  { LGKM0;                                                                       \
    BARX                                                                         \
    __builtin_amdgcn_s_setprio(1);                                               \
    CLUSTER(1)                                                                   \
    __builtin_amdgcn_s_setprio(0);                                               \
    STGS;                                                                        \
    WT;                                                                          \
    BARX                                                                         \
    RDS }

    // prologue: tile0 -> buf0, tile1 -> buf1 (8+8 loads); vmcnt(8) confirms
    // tile0; barrier; read tile0's alpha operands. Enter steady state with
    // 8 outstanding (tile1's).
    STAGE4(0, 0);
    STAGE4(1, 64);
    WAITV8;
    BARX
    RD16(0)

    int k0c = 128, k0d = 192;   // k offsets of tiles T+2, T+3
#pragma unroll 1
    for (int it = 0; it < 15; ++it) {
        ALPHA(0)
        BETA(0, STAGE4(0, k0c), WAITV8, RD16(1))
        ALPHA(1)
        BETA(1, STAGE4(1, k0d), WAITV8, RD16(0))
        k0c += 128; k0d += 128;
    }
    // tail: tiles 30 (b0) and 31 (b1); no more staging
    ALPHA(0)
    BETA(0, NOSTG, WAITV0, RD16(1))
    ALPHA(1)
    // final beta: drain A1 reads, MFMA, fall through to epilogue
    LGKM0;
    __builtin_amdgcn_s_setprio(1);
    CLUSTER(1)
    __builtin_amdgcn_s_setprio(0);

    // epilogue: C/D layout col = lane&15 (n), row = quad*4 + reg (m); fuse bias
#pragma unroll
    for (int nh = 0; nh < 2; ++nh)
#pragma unroll
        for (int ni = 0; ni < 2; ++ni) {
            const int col = bn * BN + nh * 128 + ni * 64 + wc16 + mrow;
            const float bv = bias[col];
#pragma unroll
            for (int mh = 0; mh < 2; ++mh)
#pragma unroll
                for (int mi = 0; mi < 4; ++mi) {
                    const int row0 = bm * BM + mh * 128 + mi * 32 + wr16 + quad * 4;
#pragma unroll
                    for (int r = 0; r < 4; ++r)
                        C[(size_t)(row0 + r) * N_TOT + col] =
                            acc[mh * 4 + mi][nh * 2 + ni][r] + bv;
                }
        }
#undef ALPHA
#undef BETA
#undef CLUSTER
#undef STAGE
#undef STAGE4
#undef RD_A
#undef RD_B
#undef RD16
#undef BARX
#undef LGKM0
#undef WAITV8
#undef WAITV0
#undef NOSTG
}

// ---- Fallback GEMM (proven 128^2 kernel, 32 KiB static LDS) ----
#define FBM 128
#define FBN 128
#define FBK 64
__global__ __launch_bounds__(256) void gemm_bias_kernel_128(
    const unsigned short* __restrict__ A,
    const unsigned short* __restrict__ Bw,
    const float* __restrict__ bias,
    float* __restrict__ C)
{
    __shared__ unsigned short Asm[FBM * FBK];
    __shared__ unsigned short Bsm[FBN * FBK];

    const int tid  = threadIdx.x;
    const int lane = tid & 63;
    const int wave = tid >> 6;
    const int bm = blockIdx.y;
    const int bn = blockIdx.x;

    const int srow_l = lane >> 3;
    const int schunk = ((lane & 7) ^ srow_l) * 8;
    const unsigned short* a_g[4];
    const unsigned short* b_g[4];
    unsigned short* a_l[4];
    unsigned short* b_l[4];
#pragma unroll
    for (int l = 0; l < 4; ++l) {
        const int row = wave * 32 + l * 8 + srow_l;
        a_g[l] = A  + (size_t)(bm * FBM + row) * K_TOT + schunk;
        b_g[l] = Bw + (size_t)(bn * FBN + row) * K_TOT + schunk;
        a_l[l] = Asm + (wave * 32 + l * 8) * FBK;
        b_l[l] = Bsm + (wave * 32 + l * 8) * FBK;
    }

    const int wm = (wave >> 1) * 64;
    const int wn = (wave & 1) * 64;
    const int mrow = lane & 15;
    const int quad = lane >> 4;
    const int rx   = mrow & 7;

    float4v acc[4][4] = {};

    for (int k0 = 0; k0 < K_TOT; k0 += FBK) {
        __syncthreads();
#pragma unroll
        for (int l = 0; l < 4; ++l)
            __builtin_amdgcn_global_load_lds(
                (const __attribute__((address_space(1))) unsigned int*)(a_g[l] + k0),
                (__attribute__((address_space(3))) unsigned int*)a_l[l], 16, 0, 0);
#pragma unroll
        for (int l = 0; l < 4; ++l)
            __builtin_amdgcn_global_load_lds(
                (const __attribute__((address_space(1))) unsigned int*)(b_g[l] + k0),
                (__attribute__((address_space(3))) unsigned int*)b_l[l], 16, 0, 0);
        __syncthreads();

#pragma unroll
        for (int ks = 0; ks < 2; ++ks) {
            short8 af[4], bf_[4];
#pragma unroll
            for (int mi = 0; mi < 4; ++mi) {
                const int r = wm + mi * 16 + mrow;
                const int slot = (ks * 4 + quad) ^ rx;
                af[mi] = *(const short8*)(Asm + r * FBK + slot * 8);
            }
#pragma unroll
            for (int ni = 0; ni < 4; ++ni) {
                const int r = wn + ni * 16 + mrow;
                const int slot = (ks * 4 + quad) ^ rx;
                bf_[ni] = *(const short8*)(Bsm + r * FBK + slot * 8);
            }
#pragma unroll
            for (int mi = 0; mi < 4; ++mi)
#pragma unroll
                for (int ni = 0; ni < 4; ++ni)
                    acc[mi][ni] = __builtin_amdgcn_mfma_f32_16x16x32_bf16(
                        af[mi], bf_[ni], acc[mi][ni], 0, 0, 0);
        }
    }

#pragma unroll
    for (int ni = 0; ni < 4; ++ni) {
        const int col = bn * FBN + wn + ni * 16 + mrow;
        const float bv = bias[col];
#pragma unroll
        for (int mi = 0; mi < 4; ++mi) {
#pragma unroll
            for (int r = 0; r < 4; ++r) {
                const int row = bm * FBM + wm + mi * 16 + quad * 4 + r;
                C[(size_t)row * N_TOT + col] = acc[mi][ni][r] + bv;
            }
        }
    }
}

extern "C" void kernel_launch(void* const* d_in, const int* in_sizes, int n_in,
                              void* d_out, int out_size, void* d_ws, size_t ws_size,
                              hipStream_t stream) {
    const float* x       = (const float*)d_in[0];
    const float* W_val   = (const float*)d_in[1];
    const float* bias    = (const float*)d_in[2];
    const int*   indices = (const int*)d_in[3];
    const int*   indptr  = (const int*)d_in[4];
    float* out = (float*)d_out;

    // workspace: [x_bf16: 16384*2048*2 = 64 MiB][W_bf16: 2048*2048*2 = 8 MiB]
    unsigned short* xb = (unsigned short*)d_ws;
    unsigned short* Wb = xb + (size_t)M_TOT * K_TOT;
    if (ws_size < ((size_t)M_TOT * K_TOT + (size_t)N_TOT * K_TOT) * sizeof(unsigned short))
        return;

    // 128 KiB dynamic LDS requires raising the attribute (host-side config
    // call, capture-safe). If it fails, fall back to the proven 128^2 kernel.
    hipError_t attr_ok = hipFuncSetAttribute(
        reinterpret_cast<const void*>(gemm_bias_kernel_256),
        hipFuncAttributeMaxDynamicSharedMemorySize, 131072);

    // 1) fused prep: densify W + cast x (one dispatch)
    prep_kernel<<<W_BLOCKS + CAST_BLOCKS, 256, 0, stream>>>(x, W_val, indices, indptr, xb, Wb);

    // 2) GEMM + bias
    if (attr_ok == hipSuccess) {
        gemm_bias_kernel_256<<<dim3(512), 512, 131072, stream>>>(xb, Wb, bias, out);
    } else {
        dim3 grid(N_TOT / FBN, M_TOT / FBM);  // (16, 128)
        gemm_bias_kernel_128<<<grid, 256, 0, stream>>>(xb, Wb, bias, out);
    }
}